// Round 6
// baseline (171.366 us; speedup 1.0000x reference)
//
#include <hip/hip_runtime.h>

#define POS_IN 63
#define HID 128
#define TOTAL 8789
#define NB 32
#define NPTS 65536

#define PB_OFF 8064
#define SW_OFF 8192
#define SB_OFF 8320
#define CW_OFF 8321
#define CB_OFF 8786

#define BLOCKS_PER_BATCH 32
#define PTS_PER_BLOCK (NPTS / BLOCKS_PER_BATCH) /* 2048 */
#define ITERS (PTS_PER_BLOCK / 256)             /* 8 */

typedef __attribute__((ext_vector_type(8))) short s16x8;
typedef __attribute__((ext_vector_type(4))) float f32x4;
typedef __bf16 bf16x2 __attribute__((ext_vector_type(2)));

// f32 -> bf16 RNE, integer path (setup only; proven R2)
__device__ __forceinline__ unsigned short f2bf(float v) {
    unsigned u = __builtin_bit_cast(unsigned, v);
    unsigned r = 0x7fffu + ((u >> 16) & 1u);
    return (unsigned short)((u + r) >> 16);
}
// hot-path pack: native __bf16 casts -> compiler emits v_cvt_pk_bf16_f32
__device__ __forceinline__ unsigned pk2(float a, float b) {
    bf16x2 v;
    v[0] = (__bf16)a;
    v[1] = (__bf16)b;
    return __builtin_bit_cast(unsigned, v);
}

// KEEP __launch_bounds__(256, 2): the (256,4) variant mis-executes (R3/R4,
// absmax ~0.6) — forcing the unified VGPR+AGPR file under 128 breaks codegen.
// Instead we lower natural register pressure below 128 (bias-in-K removes
// pb_v) so 4 waves/SIMD become possible without the forcing attribute.
__global__ __launch_bounds__(256, 2) void nerf_mlp_kernel(
        const float* __restrict__ params,
        const float* __restrict__ points,
        const float* __restrict__ dirs,
        float* __restrict__ out)
{
    // LDS: [0,32768) per-wave enc buffers (8KB each), aliased at start by the
    // pw bf16 stage ([128][72] ushort = 18432B). [32768,36864) = colpart.
    // 36864B/block -> 4 blocks/CU by LDS.
    __shared__ __align__(16) unsigned char smem[36864];
    unsigned short* stage = (unsigned short*)smem;

    const int tid = threadIdx.x;
    const int lane = tid & 63;
    const int wid = tid >> 6;
    const int b = blockIdx.y;
    const float* P = params + (size_t)b * TOTAL;

    // ---- stage pw (128x63) as bf16, row stride 72; k=63 column = layer-1
    // bias (bias-in-K: e[63]=1.0)
    for (int idx = tid; idx < 8064; idx += 256) {
        int n = idx / 63;
        int k = idx - n * 63;
        stage[n * 72 + k] = f2bf(P[idx]);
        if (k == 0) stage[n * 72 + 63] = f2bf(P[PB_OFF + n]);
    }
    __syncthreads();

    const int c = lane & 15;   // col-in-tile (h index low bits / point-in-tile)
    const int kg = lane >> 4;  // k-group 0..3

    // ---- 16 persistent B fragments (pw^T): lane holds
    // B[k=(kh*32)+kg*8 .. +8][n=nt*16+c] = pw[n][k..k+7]
    s16x8 wB[8][2];
    #pragma unroll
    for (int nt = 0; nt < 8; ++nt) {
        #pragma unroll
        for (int kh = 0; kh < 2; ++kh) {
            int n = nt * 16 + c;
            int k = kh * 32 + kg * 8;
            uint4 raw = *(const uint4*)&stage[n * 72 + k];
            wB[nt][kh] = __builtin_bit_cast(s16x8, raw);
        }
    }
    __syncthreads();   // stage area now reusable as enc buffers

    // ---- per-lane persistent epilogue weights (index depends only on c)
    float sw_v[8], cw0_v[8], cw1_v[8], cw2_v[8];
    #pragma unroll
    for (int nt = 0; nt < 8; ++nt) {
        int hh = nt * 16 + c;
        sw_v[nt]  = P[SW_OFF + hh];
        cw0_v[nt] = P[CW_OFF + 0 * 155 + hh];
        cw1_v[nt] = P[CW_OFF + 1 * 155 + hh];
        cw2_v[nt] = P[CW_OFF + 2 * 155 + hh];
    }
    const int oo = lane & 3;          // output channel this lane stores
    const int jj = (lane & 15) >> 2;  // point-reg this lane stores
    const float cbias = P[oo < 3 ? (CB_OFF + oo) : SB_OFF];

    unsigned char* encb = smem + wid * 8192;            // [kq][p][8] bf16
    float* cpb = (float*)(smem + 32768 + wid * 1024);   // [64][4] f32 colpart

    const size_t bpts = (size_t)b * NPTS;
    const int n0b = blockIdx.x * PTS_PER_BLOCK;

    for (int it = 0; it < ITERS; ++it) {
        const int n0 = n0b + it * 256 + wid * 64;  // this wave's 64-point chunk
        const int p = n0 + lane;

        const float* pp = points + (bpts + p) * 3;
        float x = pp[0], y = pp[1], z = pp[2];
        const float* dd = dirs + (bpts + p) * 3;
        float dx = dd[0], dy = dd[1], dz = dd[2];

        // ---- positional encoding (63 + bias slot), sincos via angle doubling
        float e[64];
        e[0] = x; e[1] = y; e[2] = z; e[63] = 1.0f;   // 1.0 hits bias row of wB
        #pragma unroll
        for (int i = 0; i < 3; ++i) {
            float v = (i == 0) ? x : (i == 1) ? y : z;
            float s = __sinf(v), co = __cosf(v);
            e[3 + i * 10] = s; e[33 + i * 10] = co;
            #pragma unroll
            for (int f = 1; f < 10; ++f) {
                float ns = 2.f * s * co;
                float nc = 1.f - 2.f * s * s;
                s = ns; co = nc;
                e[3 + i * 10 + f] = s;
                e[33 + i * 10 + f] = co;
            }
        }

        // ---- dir encoding folded directly into color partials (SGPR weights)
        float cp0 = 0.f, cp1 = 0.f, cp2 = 0.f;
        #pragma unroll
        for (int i = 0; i < 3; ++i) {
            float v = (i == 0) ? dx : (i == 1) ? dy : dz;
            cp0 = fmaf(v, P[CW_OFF + 128 + i], cp0);
            cp1 = fmaf(v, P[CW_OFF + 155 + 128 + i], cp1);
            cp2 = fmaf(v, P[CW_OFF + 310 + 128 + i], cp2);
            float s = __sinf(v), co = __cosf(v);
            #pragma unroll
            for (int f = 0; f < 4; ++f) {
                if (f > 0) {
                    float ns = 2.f * s * co;
                    float nc = 1.f - 2.f * s * s;
                    s = ns; co = nc;
                }
                int si = 128 + 3 + i * 4 + f;
                int ci = 128 + 15 + i * 4 + f;
                cp0 = fmaf(s, P[CW_OFF + si], cp0);
                cp1 = fmaf(s, P[CW_OFF + 155 + si], cp1);
                cp2 = fmaf(s, P[CW_OFF + 310 + si], cp2);
                cp0 = fmaf(co, P[CW_OFF + ci], cp0);
                cp1 = fmaf(co, P[CW_OFF + 155 + ci], cp1);
                cp2 = fmaf(co, P[CW_OFF + 310 + ci], cp2);
            }
        }
        *(float4*)(cpb + lane * 4) = make_float4(cp0, cp1, cp2, 0.f);

        // ---- pack enc to LDS (bf16), layout [kq][point][8]
        #pragma unroll
        for (int kq = 0; kq < 8; ++kq) {
            uint4 q;
            q.x = pk2(e[kq * 8 + 0], e[kq * 8 + 1]);
            q.y = pk2(e[kq * 8 + 2], e[kq * 8 + 3]);
            q.z = pk2(e[kq * 8 + 4], e[kq * 8 + 5]);
            q.w = pk2(e[kq * 8 + 6], e[kq * 8 + 7]);
            *(uint4*)(encb + kq * 1024 + lane * 16) = q;
        }

        float* outp = out + (bpts + n0) * 4;

        // ---- 4 m-tiles of 16 points
        #pragma unroll
        for (int t = 0; t < 4; ++t) {
            uint4 a0r = *(const uint4*)(encb + kg * 1024 + (t * 16 + c) * 16);
            uint4 a1r = *(const uint4*)(encb + (4 + kg) * 1024 + (t * 16 + c) * 16);
            s16x8 A0 = __builtin_bit_cast(s16x8, a0r);
            s16x8 A1 = __builtin_bit_cast(s16x8, a1r);

            f32x4 acc[8];
            #pragma unroll
            for (int nt = 0; nt < 8; ++nt) {
                acc[nt] = (f32x4){0.f, 0.f, 0.f, 0.f};  // bias comes via K=63
                acc[nt] = __builtin_amdgcn_mfma_f32_16x16x32_bf16(A0, wB[nt][0], acc[nt], 0, 0, 0);
                acc[nt] = __builtin_amdgcn_mfma_f32_16x16x32_bf16(A1, wB[nt][1], acc[nt], 0, 0, 0);
            }

            // D layout: col = nt*16 + (lane&15) = h index, row = kg*4 + j = point
            float sg[4] = {0,0,0,0}, c0[4] = {0,0,0,0}, c1[4] = {0,0,0,0}, c2[4] = {0,0,0,0};
            #pragma unroll
            for (int j = 0; j < 4; ++j) {
                #pragma unroll
                for (int nt = 0; nt < 8; ++nt) {
                    float hv = fmaxf(acc[nt][j], 0.f);   // relu(h + pb)
                    sg[j] = fmaf(hv, sw_v[nt], sg[j]);
                    c0[j] = fmaf(hv, cw0_v[nt], c0[j]);
                    c1[j] = fmaf(hv, cw1_v[nt], c1[j]);
                    c2[j] = fmaf(hv, cw2_v[nt], c2[j]);
                }
            }
            // 16-lane butterfly reduction (stays within lane group kg)
            #pragma unroll
            for (int m = 1; m <= 8; m <<= 1) {
                #pragma unroll
                for (int j = 0; j < 4; ++j) {
                    sg[j] += __shfl_xor(sg[j], m, 64);
                    c0[j] += __shfl_xor(c0[j], m, 64);
                    c1[j] += __shfl_xor(c1[j], m, 64);
                    c2[j] += __shfl_xor(c2[j], m, 64);
                }
            }
            // lane (kg, jj, oo) -> point t*16+kg*4+jj, channel oo
            float a0 = (oo == 0) ? c0[0] : (oo == 1) ? c1[0] : (oo == 2) ? c2[0] : sg[0];
            float a1 = (oo == 0) ? c0[1] : (oo == 1) ? c1[1] : (oo == 2) ? c2[1] : sg[1];
            float a2 = (oo == 0) ? c0[2] : (oo == 1) ? c1[2] : (oo == 2) ? c2[2] : sg[2];
            float a3 = (oo == 0) ? c0[3] : (oo == 1) ? c1[3] : (oo == 2) ? c2[3] : sg[3];
            float val = (jj == 0) ? a0 : (jj == 1) ? a1 : (jj == 2) ? a2 : a3;

            val += cpb[t * 64 + lane] + cbias;  // dir-branch of color (0 for sigma) + bias
            float sig = 1.f / (1.f + __expf(-val));
            val = (oo < 3) ? sig : val;         // sigmoid on color only

            outp[t * 64 + lane] = val;          // fully coalesced: offset = t*64+lane
        }
    }
}

extern "C" void kernel_launch(void* const* d_in, const int* in_sizes, int n_in,
                              void* d_out, int out_size, void* d_ws, size_t ws_size,
                              hipStream_t stream) {
    const float* params = (const float*)d_in[0];
    const float* points = (const float*)d_in[1];
    const float* dirs   = (const float*)d_in[2];
    float* out = (float*)d_out;
    dim3 grid(BLOCKS_PER_BATCH, NB);
    nerf_mlp_kernel<<<grid, 256, 0, stream>>>(params, points, dirs, out);
}

// Round 7
// 90.774 us; speedup vs baseline: 1.8878x; 1.8878x over previous
//
#include <hip/hip_runtime.h>

#define POS_IN 63
#define HID 128
#define TOTAL 8789
#define NB 32
#define NPTS 65536

#define PB_OFF 8064
#define SW_OFF 8192
#define SB_OFF 8320
#define CW_OFF 8321
#define CB_OFF 8786

#define BLOCKS_PER_BATCH 32
#define PTS_PER_BLOCK (NPTS / BLOCKS_PER_BATCH) /* 2048 */
#define ITERS (PTS_PER_BLOCK / 256)             /* 8 */

typedef __attribute__((ext_vector_type(8))) short s16x8;
typedef __attribute__((ext_vector_type(4))) float f32x4;
typedef __bf16 bf16x2 __attribute__((ext_vector_type(2)));

// f32 -> bf16 RNE, integer path (setup only; proven R2)
__device__ __forceinline__ unsigned short f2bf(float v) {
    unsigned u = __builtin_bit_cast(unsigned, v);
    unsigned r = 0x7fffu + ((u >> 16) & 1u);
    return (unsigned short)((u + r) >> 16);
}
// hot-path pack: native __bf16 casts -> v_cvt_pk_bf16_f32 (proven R6)
__device__ __forceinline__ unsigned pk2(float a, float b) {
    bf16x2 v;
    v[0] = (__bf16)a;
    v[1] = (__bf16)b;
    return __builtin_bit_cast(unsigned, v);
}

// KEEP __launch_bounds__(256,2): (256,4) mis-executes (R3/R4). Occupancy is
// instead sought by getting arch-VGPR + AGPR <= 128 (unified file, m69
// halving points) so HW runs 4 waves/SIMD naturally.
__global__ __launch_bounds__(256, 2) void nerf_mlp_kernel(
        const float* __restrict__ params,
        const float* __restrict__ points,
        const float* __restrict__ dirs,
        float* __restrict__ out)
{
    // LDS: [0,32768) per-wave enc buffers (8KB each), aliased at start by the
    // pw bf16 stage ([128][72] ushort = 18432B). [32768,37888) = per-wave
    // hbuf (1280B each): layer-2 transpose bounce + output bounce (256B).
    // 37888B/block -> 4 blocks/CU by LDS.
    __shared__ __align__(16) unsigned char smem[37888];
    unsigned short* stage = (unsigned short*)smem;

    const int tid = threadIdx.x;
    const int lane = tid & 63;
    const int wid = tid >> 6;
    const int b = blockIdx.y;
    const float* P = params + (size_t)b * TOTAL;

    // ---- stage pw (128x63) as bf16, row stride 72; k=63 column = layer-1
    // bias (bias-in-K: e[63]=1.0)
    for (int idx = tid; idx < 8064; idx += 256) {
        int n = idx / 63;
        int k = idx - n * 63;
        stage[n * 72 + k] = f2bf(P[idx]);
        if (k == 0) stage[n * 72 + 63] = f2bf(P[PB_OFF + n]);
    }
    __syncthreads();

    const int c = lane & 15;   // tile col: point-in-tile (and h low bits for wB)
    const int kg = lane >> 4;  // k-group 0..3

    // ---- 16 persistent layer-1 fragments: lane holds pw[n=nt*16+c][k slice]
    s16x8 wB[8][2];
    #pragma unroll
    for (int nt = 0; nt < 8; ++nt) {
        #pragma unroll
        for (int kh = 0; kh < 2; ++kh) {
            int n = nt * 16 + c;
            int k = kh * 32 + kg * 8;
            uint4 raw = *(const uint4*)&stage[n * 72 + k];
            wB[nt][kh] = __builtin_bit_cast(s16x8, raw);
        }
    }
    __syncthreads();   // stage area now reusable as enc buffers

    // ---- layer-2 weight fragments (persistent, 16 VGPR): B2[k=h][col=o]
    // o = c: 0..2 = color rows (cw), 3 = sigma row (sw); cols 4..15 zero.
    s16x8 wB2[4];
    #pragma unroll
    for (int m = 0; m < 4; ++m) {
        unsigned d0 = 0, d1 = 0, d2 = 0, d3 = 0;
        if (c < 4) {
            const int base = (c == 3) ? SW_OFF : (CW_OFF + c * 155);
            const int h0 = m * 32 + kg * 8;
            d0 = pk2(P[base + h0 + 0], P[base + h0 + 1]);
            d1 = pk2(P[base + h0 + 2], P[base + h0 + 3]);
            d2 = pk2(P[base + h0 + 4], P[base + h0 + 5]);
            d3 = pk2(P[base + h0 + 6], P[base + h0 + 7]);
        }
        uint4 dd = make_uint4(d0, d1, d2, d3);
        wB2[m] = __builtin_bit_cast(s16x8, dd);
    }

    const int ch = lane & 3;          // output channel this lane stores
    const float cbias = P[ch < 3 ? (CB_OFF + ch) : SB_OFF];

    unsigned char* encb = smem + wid * 8192;           // [kq][p][8] bf16
    unsigned char* hbuf = smem + 32768 + wid * 1280;   // [16pt][40B] bf16 bounce

    const size_t bpts = (size_t)b * NPTS;
    const int n0b = blockIdx.x * PTS_PER_BLOCK;

    for (int it = 0; it < ITERS; ++it) {
        const int n0 = n0b + it * 256 + wid * 64;  // this wave's 64-point chunk
        const int p = n0 + lane;

        const float* pp = points + (bpts + p) * 3;
        float x = pp[0], y = pp[1], z = pp[2];
        const float* dd = dirs + (bpts + p) * 3;
        float dx = dd[0], dy = dd[1], dz = dd[2];

        // ---- positional encoding (63 + bias slot), sincos via angle doubling
        float e[64];
        e[0] = x; e[1] = y; e[2] = z; e[63] = 1.0f;   // 1.0 hits bias row of wB
        #pragma unroll
        for (int i = 0; i < 3; ++i) {
            float v = (i == 0) ? x : (i == 1) ? y : z;
            float s = __sinf(v), co = __cosf(v);
            e[3 + i * 10] = s; e[33 + i * 10] = co;
            #pragma unroll
            for (int f = 1; f < 10; ++f) {
                float ns = 2.f * s * co;
                float nc = 1.f - 2.f * s * s;
                s = ns; co = nc;
                e[3 + i * 10 + f] = s;
                e[33 + i * 10 + f] = co;
            }
        }

        // ---- dir encoding folded into per-point color partials (3 regs)
        float cp0 = 0.f, cp1 = 0.f, cp2 = 0.f;
        #pragma unroll
        for (int i = 0; i < 3; ++i) {
            float v = (i == 0) ? dx : (i == 1) ? dy : dz;
            cp0 = fmaf(v, P[CW_OFF + 128 + i], cp0);
            cp1 = fmaf(v, P[CW_OFF + 155 + 128 + i], cp1);
            cp2 = fmaf(v, P[CW_OFF + 310 + 128 + i], cp2);
            float s = __sinf(v), co = __cosf(v);
            #pragma unroll
            for (int f = 0; f < 4; ++f) {
                if (f > 0) {
                    float ns = 2.f * s * co;
                    float nc = 1.f - 2.f * s * s;
                    s = ns; co = nc;
                }
                int si = 128 + 3 + i * 4 + f;
                int ci = 128 + 15 + i * 4 + f;
                cp0 = fmaf(s, P[CW_OFF + si], cp0);
                cp1 = fmaf(s, P[CW_OFF + 155 + si], cp1);
                cp2 = fmaf(s, P[CW_OFF + 310 + si], cp2);
                cp0 = fmaf(co, P[CW_OFF + ci], cp0);
                cp1 = fmaf(co, P[CW_OFF + 155 + ci], cp1);
                cp2 = fmaf(co, P[CW_OFF + 310 + ci], cp2);
            }
        }

        // ---- pack enc to LDS (bf16), layout [kq][point][8]
        #pragma unroll
        for (int kq = 0; kq < 8; ++kq) {
            uint4 q;
            q.x = pk2(e[kq * 8 + 0], e[kq * 8 + 1]);
            q.y = pk2(e[kq * 8 + 2], e[kq * 8 + 3]);
            q.z = pk2(e[kq * 8 + 4], e[kq * 8 + 5]);
            q.w = pk2(e[kq * 8 + 6], e[kq * 8 + 7]);
            *(uint4*)(encb + kq * 1024 + lane * 16) = q;
        }

        float* outp = out + (bpts + n0) * 4;

        // ---- 4 m-tiles of 16 points
        #pragma unroll
        for (int t = 0; t < 4; ++t) {
            uint4 a0r = *(const uint4*)(encb + kg * 1024 + (t * 16 + c) * 16);
            uint4 a1r = *(const uint4*)(encb + (4 + kg) * 1024 + (t * 16 + c) * 16);
            s16x8 A0 = __builtin_bit_cast(s16x8, a0r);
            s16x8 A1 = __builtin_bit_cast(s16x8, a1r);

            // SWAPPED layer-1: D[h][pt] -> lane (c,kg) reg j holds
            // h = nt*16 + kg*4 + j, pt = t*16 + c  (pt on lane&15 for layer-2 A)
            f32x4 acc[8];
            #pragma unroll
            for (int nt = 0; nt < 8; ++nt) {
                acc[nt] = (f32x4){0.f, 0.f, 0.f, 0.f};  // bias comes via K=63
                acc[nt] = __builtin_amdgcn_mfma_f32_16x16x32_bf16(wB[nt][0], A0, acc[nt], 0, 0, 0);
                acc[nt] = __builtin_amdgcn_mfma_f32_16x16x32_bf16(wB[nt][1], A1, acc[nt], 0, 0, 0);
            }
            // relu in place
            #pragma unroll
            for (int nt = 0; nt < 8; ++nt)
                #pragma unroll
                for (int j = 0; j < 4; ++j)
                    acc[nt][j] = fmaxf(acc[nt][j], 0.f);

            // ---- layer-2: 4 MFMAs, K=128 in 4 chunks, via LDS transpose
            // bounce. hbuf row = pt-local (c), stride 80B, chunk-local h.
            f32x4 acc2 = (f32x4){0.f, 0.f, 0.f, 0.f};
            #pragma unroll
            for (int m = 0; m < 4; ++m) {
                unsigned q0 = pk2(acc[2 * m][0], acc[2 * m][1]);
                unsigned q1 = pk2(acc[2 * m][2], acc[2 * m][3]);
                unsigned q2 = pk2(acc[2 * m + 1][0], acc[2 * m + 1][1]);
                unsigned q3 = pk2(acc[2 * m + 1][2], acc[2 * m + 1][3]);
                // h_local: nt=2m -> kg*4, nt=2m+1 -> 16+kg*4 (bf16 units)
                *(uint2*)(hbuf + c * 80 + kg * 8)      = make_uint2(q0, q1);
                *(uint2*)(hbuf + c * 80 + 32 + kg * 8) = make_uint2(q2, q3);
                // A2 frag: row=pt(c), k-slice kg*8..+8  (same-wave DS is
                // in-order: read after write needs no barrier)
                uint4 ar = *(const uint4*)(hbuf + c * 80 + kg * 16);
                s16x8 A2 = __builtin_bit_cast(s16x8, ar);
                acc2 = __builtin_amdgcn_mfma_f32_16x16x32_bf16(A2, wB2[m], acc2, 0, 0, 0);
            }

            // D2: lane (c,kg) reg j = out(pt=t*16+kg*4+j, o=c), valid c<4.
            // Bounce through hbuf[0..255] to get coalesced stores.
            if (c < 4) {
                #pragma unroll
                for (int j = 0; j < 4; ++j)
                    ((float*)hbuf)[(kg * 4 + j) * 4 + c] = acc2[j];
            }
            float v = ((float*)hbuf)[lane];

            // color partial of this lane's point (computed on lane t*16+pt)
            int src = t * 16 + (lane >> 2);
            float p0 = __shfl(cp0, src, 64);
            float p1 = __shfl(cp1, src, 64);
            float p2 = __shfl(cp2, src, 64);
            float cpv = (ch == 0) ? p0 : (ch == 1) ? p1 : (ch == 2) ? p2 : 0.f;

            v += cpv + cbias;
            float sig = 1.f / (1.f + __expf(-v));
            v = (ch < 3) ? sig : v;             // sigmoid on color only

            outp[t * 64 + lane] = v;            // coalesced: offset = t*64+lane
        }
    }
}

extern "C" void kernel_launch(void* const* d_in, const int* in_sizes, int n_in,
                              void* d_out, int out_size, void* d_ws, size_t ws_size,
                              hipStream_t stream) {
    const float* params = (const float*)d_in[0];
    const float* points = (const float*)d_in[1];
    const float* dirs   = (const float*)d_in[2];
    float* out = (float*)d_out;
    dim3 grid(BLOCKS_PER_BATCH, NB);
    nerf_mlp_kernel<<<grid, 256, 0, stream>>>(params, points, dirs, out);
}